// Round 14
// baseline (226.007 us; speedup 1.0000x reference)
//
#include <hip/hip_runtime.h>
#include <stdint.h>
#include <stddef.h>

// BinarizeLinearWithFoldedBN on MI355X (gfx950).
// out[b,o] = dot(sign(x[b,:]), sign(w[o,:])) * scale[o] + bias[o]
//   scale = gamma/sqrt(var+eps), bias = beta - mean*scale (exact BN algebra)
// FP4 (+/-1 in e2m1) MFMA GEMM via v_mfma_f32_16x16x128_f8f6f4 cbsz:4 blgp:4.
// 256x256 tile, 16 waves (4x4 grid, 64x64/wave, 64-reg acc). A: LDS 4-buf
// 64B-slab rotation, distance-3 prefetch, T2 granule involution (0 conflicts).
// B: DIRECT per-lane global loads (L2-resident, no swizzle needed) -- halves
// LDS-pipe traffic, which R13 showed was the bottleneck. T1 XCD swizzle +
// T5 setprio. Exact f32 accum of +/-1.

#define BN_EPS 1e-5f
typedef int   v4i __attribute__((ext_vector_type(4)));
typedef float v4f __attribute__((ext_vector_type(4)));
typedef unsigned int u32;

// ---------------- BN fold ----------------
__global__ void bn_prep_kernel(const float* __restrict__ g, const float* __restrict__ b,
                               const float* __restrict__ m, const float* __restrict__ v,
                               float* __restrict__ scale, float* __restrict__ bias, int n) {
  int i = blockIdx.x * blockDim.x + threadIdx.x;
  if (i >= n) return;
  float s = g[i] * rsqrtf(v[i] + BN_EPS);
  scale[i] = s;
  bias[i] = b[i] - m[i] * s;
}

// ---------------- pack f32 signs -> fp4 e2m1 +/-1 nibbles ----------------
// +1 -> 0x2, -1 -> 0xA. 32 floats (8 uint4) -> 16 nibble-packed bytes.
__global__ __launch_bounds__(256) void pack_sign_fp4_kernel(
    const uint4* __restrict__ in, uint4* __restrict__ outp, int n32) {
  int t = blockIdx.x * blockDim.x + threadIdx.x;
  if (t >= n32) return;
  const uint4* p = in + (size_t)t * 8;
  u32 w[4];
#pragma unroll
  for (int j = 0; j < 4; ++j) {
    uint4 u0 = p[2 * j];
    uint4 u1 = p[2 * j + 1];
    u32 h0 = 0x2222u | ((u0.x >> 28) & 0x8u) | (((u0.y >> 28) & 0x8u) << 4)
                     | (((u0.z >> 28) & 0x8u) << 8) | (((u0.w >> 28) & 0x8u) << 12);
    u32 h1 = 0x2222u | ((u1.x >> 28) & 0x8u) | (((u1.y >> 28) & 0x8u) << 4)
                     | (((u1.z >> 28) & 0x8u) << 8) | (((u1.w >> 28) & 0x8u) << 12);
    w[j] = h0 | (h1 << 16);
  }
  uint4 o; o.x = w[0]; o.y = w[1]; o.z = w[2]; o.w = w[3];
  outp[t] = o;
}

// ---------------- fp4 MFMA GEMM ----------------
// Row bytes RB = IN/2. LDS (64 KiB): A slab buf q (q=0..3): q*16384 (256 x 64 B).
// One slab = 64 B/row = K=128 = one MFMA k-step.
// T2 granule involution (A only): LDS(row R, chunk C) = global granule C ^ ((R>>1)&3);
//   write: linear gload_lds dest + pre-swizzled SOURCE granule;
//   read: chunk = (lane>>4) ^ ((ln15>>1)&3)   [R11/R13: 0 conflicts].
// B frags: plain global reads, chunk = (lane>>4)*16 (same lane->k map as A).

#define BAR() asm volatile("s_barrier" ::: "memory")
#define WAITV(n) asm volatile("s_waitcnt vmcnt(" #n ")" ::: "memory")
#define LGKM0() asm volatile("s_waitcnt lgkmcnt(0)" ::: "memory")

// fp4 (cbsz:4 / blgp:4): A and B are 4-dword register tuples; acc = 4 x f32
#define MFMA16x16(accv, av, bv) \
  asm("v_mfma_f32_16x16x128_f8f6f4 %0, %1, %2, %0 cbsz:4 blgp:4" \
      : "+v"(accv) : "v"(av), "v"(bv))

__global__ __launch_bounds__(1024, 4) void bgemm_fp4_bd(
    const int8_t* __restrict__ A4, const int8_t* __restrict__ B4,
    const float* __restrict__ scale, const float* __restrict__ bias,
    float* __restrict__ out, int M, int N, int RB /* = IN/2 bytes per row */) {
  __shared__ __align__(16) int8_t lds[65536];

  const int tid = threadIdx.x;
  const int lane = tid & 63;
  const int wid = tid >> 6;      // 0..15
  const int wm = wid >> 2;       // 0..3  (64-row band)
  const int wn = wid & 3;        // 0..3  (64-col band)

  // T1: bijective XCD swizzle (nwg % 8 == 0 here: 32*16 = 512)
  const int nbx = N >> 8;
  const int nwg = (M >> 8) * nbx;
  const int cpx = nwg >> 3;
  const int bid = (int)blockIdx.x;
  const int swz = (bid & 7) * cpx + (bid >> 3);
  const int row0 = (swz / nbx) << 8;
  const int col0 = (swz % nbx) << 8;

  const int ln15 = lane & 15;
  // T2 read-side swizzle (A, verified): chunk byte offset
  const int kcs = (((lane >> 4) ^ ((ln15 >> 1) & 3)) << 4);
  const int aoff = (wm * 64 + ln15) * 64 + kcs;    // + m*1024, m=0..3

  // staging (A only): wave wid stages rows wid*16..wid*16+15 (1 KB)
  const int srow = wid * 16 + (lane >> 2);
  const int sch = (((lane & 3) ^ ((lane >> 3) & 3)) << 4);  // pre-swizzled source granule
  const int ldw = wid << 10;                // wave slot: 1 KB

  const int8_t* aSt = A4 + (size_t)(row0 + srow) * RB + sch;
  // B direct-load base: lane covers col (ln15 within n-tile), k-chunk (lane>>4)
  const size_t nstr = (size_t)16 * RB;      // 16 rows of B per n-tile step
  const int8_t* bGl = B4 + (size_t)(col0 + wn * 64 + ln15) * RB + ((lane >> 4) << 4);

  v4f acc[4][4];
#pragma unroll
  for (int i = 0; i < 4; ++i)
#pragma unroll
    for (int n = 0; n < 4; ++n) { v4f z = {0.f, 0.f, 0.f, 0.f}; acc[i][n] = z; }

// 1 global_load_lds per wave per slab (A row-group)
#define STAGE(s) do {                                                                 \
  const int bb_ = ((s) & 3) * 16384;                                                  \
  __builtin_amdgcn_global_load_lds(                                                   \
      (const __attribute__((address_space(1))) uint32_t*)(aSt + (size_t)(s) * 64),    \
      (__attribute__((address_space(3))) uint32_t*)(lds + bb_ + ldw), 16, 0, 0);      \
} while (0)

// one K=128 slab: B frags direct from global (compiler-managed counted vmcnt
// before each use), A frags from LDS buf q. All B loads consumed in-body, so
// at the post-COMPUTE wait point exactly the 3 A-stages are outstanding.
#define COMPUTE(q, s) do {                                                            \
  const int8_t* ap_ = lds + (q) * 16384 + aoff;                                       \
  const int8_t* bp_ = bGl + (size_t)(s) * 64;                                         \
  v4i Bv0 = *(const v4i*)(bp_);            v4i Bv1 = *(const v4i*)(bp_ + nstr);       \
  v4i Bv2 = *(const v4i*)(bp_ + 2 * nstr); v4i Bv3 = *(const v4i*)(bp_ + 3 * nstr);   \
  __builtin_amdgcn_s_setprio(1);                                                      \
  _Pragma("unroll")                                                                   \
  for (int m_ = 0; m_ < 4; ++m_) {                                                    \
    v4i Av = *(const v4i*)(ap_ + m_ * 1024);                                          \
    MFMA16x16(acc[m_][0], Av, Bv0);                                                   \
    MFMA16x16(acc[m_][1], Av, Bv1);                                                   \
    MFMA16x16(acc[m_][2], Av, Bv2);                                                   \
    MFMA16x16(acc[m_][3], Av, Bv3);                                                   \
  }                                                                                   \
  __builtin_amdgcn_s_setprio(0);                                                      \
} while (0)

  const int NT = RB >> 6;   // 64-byte slabs (K=128 each); 32 for IN=4096

  // ---- prologue: prefetch A slabs 0,1,2 (3 loads); certify slab 0; BAR
  STAGE(0); STAGE(1); STAGE(2);
  WAITV(2);
  BAR();

  // ---- main loop: compute slab t, stage A slab t+3 into buf (t-1)&3
  // (readers drained at body t-1's LGKM0+BAR). WAITV(2) leaves A(t+2),A(t+3)
  // in flight and certifies A(t+1); barrier publishes it to all waves.
  for (int t = 0; t < NT - 3; ++t) {
    STAGE(t + 3);
    COMPUTE(t & 3, t);
    LGKM0();
    WAITV(2);
    BAR();
  }
  // tail: drain 2 -> 1 -> 0 outstanding A-stages
  COMPUTE((NT - 3) & 3, NT - 3); LGKM0(); WAITV(1); BAR();
  COMPUTE((NT - 2) & 3, NT - 2); LGKM0(); WAITV(0); BAR();
  COMPUTE((NT - 1) & 3, NT - 1);
  asm volatile("s_nop 7\n\ts_nop 7" :::);   // MFMA write -> VALU read hazard guard

  // ---- epilogue: 16x16 C/D layout: col = lane&15, row = (lane>>4)*4 + reg
  // (verified). acc[i] <-> rows wm*64 + i*16.
  const int cw = col0 + wn * 64;
  float scv[4], biv[4];
#pragma unroll
  for (int n = 0; n < 4; ++n) {
    int c = cw + n * 16 + ln15;
    scv[n] = scale[c];
    biv[n] = bias[c];
  }
#pragma unroll
  for (int i = 0; i < 4; ++i) {
    const int r0 = row0 + wm * 64 + i * 16 + ((lane >> 4) << 2);
#pragma unroll
    for (int reg = 0; reg < 4; ++reg) {
      float* orow = out + (size_t)(r0 + reg) * N;
#pragma unroll
      for (int n = 0; n < 4; ++n)
        orow[cw + n * 16 + ln15] = fmaf(acc[i][n][reg], scv[n], biv[n]);
    }
  }

#undef STAGE
#undef COMPUTE
}

// ======================= launch =======================
extern "C" void kernel_launch(void* const* d_in, const int* in_sizes, int n_in,
                              void* d_out, int out_size, void* d_ws, size_t ws_size,
                              hipStream_t stream) {
  const float* x = (const float*)d_in[0];
  const float* w = (const float*)d_in[1];
  const float* gamma = (const float*)d_in[2];
  const float* beta = (const float*)d_in[3];
  const float* mean = (const float*)d_in[4];
  const float* var = (const float*)d_in[5];
  float* out = (float*)d_out;

  const int OUT = in_sizes[2];            // 4096
  const int IN = in_sizes[1] / OUT;       // 4096
  const int B = in_sizes[0] / IN;         // 8192
  const int RB = IN / 2;                  // packed fp4 bytes per row

  int8_t* a4 = (int8_t*)d_ws;
  int8_t* b4 = a4 + (size_t)B * RB;
  float* scale = (float*)(b4 + (size_t)OUT * RB);
  float* bias = scale + OUT;

  const int n32x = B * (IN / 32);
  const int n32w = OUT * (IN / 32);
  pack_sign_fp4_kernel<<<(n32x + 255) / 256, 256, 0, stream>>>(
      (const uint4*)x, (uint4*)a4, n32x);
  pack_sign_fp4_kernel<<<(n32w + 255) / 256, 256, 0, stream>>>(
      (const uint4*)w, (uint4*)b4, n32w);
  bn_prep_kernel<<<(OUT + 255) / 256, 256, 0, stream>>>(
      gamma, beta, mean, var, scale, bias, OUT);

  dim3 grid((B >> 8) * (OUT >> 8));
  bgemm_fp4_bd<<<grid, 1024, 0, stream>>>(a4, b4, scale, bias, out, B, OUT, RB);
}

// Round 15
// 136.193 us; speedup vs baseline: 1.6595x; 1.6595x over previous
//
#include <hip/hip_runtime.h>
#include <stdint.h>
#include <stddef.h>

// BinarizeLinearWithFoldedBN on MI355X (gfx950).
// out[b,o] = dot(sign(x[b,:]), sign(w[o,:])) * scale[o] + bias[o]
//   scale = gamma/sqrt(var+eps), bias = beta - mean*scale (exact BN algebra)
// FP4 (+/-1 in e2m1) MFMA GEMM via v_mfma_f32_16x16x128_f8f6f4 cbsz:4 blgp:4.
// 256x256 tile, 16 waves (4x4 grid, 64x64/wave, 64-reg acc).
// A: LDS 4-buf 64B-slab rotation, distance-3 prefetch, T2 granule involution.
// B: direct per-lane global loads from a FRAGMENT-MAJOR packed layout
//    (B'[col/16][granule][col%16][16B] -> wave load is 1KB contiguous),
//    prefetched cross-barrier (issued after this slab's MFMAs, consumed next
//    slab) so L2 latency hides under the barrier + next-body head.
// T1 XCD swizzle + T5 setprio. Exact f32 accum of +/-1.

#define BN_EPS 1e-5f
typedef int   v4i __attribute__((ext_vector_type(4)));
typedef float v4f __attribute__((ext_vector_type(4)));
typedef unsigned int u32;

// ---------------- BN fold ----------------
__global__ void bn_prep_kernel(const float* __restrict__ g, const float* __restrict__ b,
                               const float* __restrict__ m, const float* __restrict__ v,
                               float* __restrict__ scale, float* __restrict__ bias, int n) {
  int i = blockIdx.x * blockDim.x + threadIdx.x;
  if (i >= n) return;
  float s = g[i] * rsqrtf(v[i] + BN_EPS);
  scale[i] = s;
  bias[i] = b[i] - m[i] * s;
}

// ---------------- pack f32 signs -> fp4 e2m1 +/-1 nibbles (row-major, for A) ----
// +1 -> 0x2, -1 -> 0xA. 32 floats (8 uint4) -> 16 nibble-packed bytes.
__global__ __launch_bounds__(256) void pack_sign_fp4_kernel(
    const uint4* __restrict__ in, uint4* __restrict__ outp, int n32) {
  int t = blockIdx.x * blockDim.x + threadIdx.x;
  if (t >= n32) return;
  const uint4* p = in + (size_t)t * 8;
  u32 w[4];
#pragma unroll
  for (int j = 0; j < 4; ++j) {
    uint4 u0 = p[2 * j];
    uint4 u1 = p[2 * j + 1];
    u32 h0 = 0x2222u | ((u0.x >> 28) & 0x8u) | (((u0.y >> 28) & 0x8u) << 4)
                     | (((u0.z >> 28) & 0x8u) << 8) | (((u0.w >> 28) & 0x8u) << 12);
    u32 h1 = 0x2222u | ((u1.x >> 28) & 0x8u) | (((u1.y >> 28) & 0x8u) << 4)
                     | (((u1.z >> 28) & 0x8u) << 8) | (((u1.w >> 28) & 0x8u) << 12);
    w[j] = h0 | (h1 << 16);
  }
  uint4 o; o.x = w[0]; o.y = w[1]; o.z = w[2]; o.w = w[3];
  outp[t] = o;
}

// ---------------- W pack: fragment-major tile layout for direct B loads ----------
// thread t: row c = t/GR, granule g = t%GR (granule = 32 elems = 16 B).
// out uint4 index = (c>>4)*(GR*16) + g*16 + (c&15)  ->  B'[c>>4][g][c&15][16B].
__global__ __launch_bounds__(256) void pack_sign_fp4_wtile(
    const uint4* __restrict__ in, uint4* __restrict__ outp, int n32, int GR) {
  int t = blockIdx.x * blockDim.x + threadIdx.x;
  if (t >= n32) return;
  const uint4* p = in + (size_t)t * 8;
  u32 w[4];
#pragma unroll
  for (int j = 0; j < 4; ++j) {
    uint4 u0 = p[2 * j];
    uint4 u1 = p[2 * j + 1];
    u32 h0 = 0x2222u | ((u0.x >> 28) & 0x8u) | (((u0.y >> 28) & 0x8u) << 4)
                     | (((u0.z >> 28) & 0x8u) << 8) | (((u0.w >> 28) & 0x8u) << 12);
    u32 h1 = 0x2222u | ((u1.x >> 28) & 0x8u) | (((u1.y >> 28) & 0x8u) << 4)
                     | (((u1.z >> 28) & 0x8u) << 8) | (((u1.w >> 28) & 0x8u) << 12);
    w[j] = h0 | (h1 << 16);
  }
  uint4 o; o.x = w[0]; o.y = w[1]; o.z = w[2]; o.w = w[3];
  const int c = t / GR;
  const int g = t - c * GR;
  outp[(size_t)(c >> 4) * (GR * 16) + g * 16 + (c & 15)] = o;
}

// ---------------- fp4 MFMA GEMM ----------------
// Row bytes RB = IN/2. LDS (64 KiB): A slab buf q (q=0..3): q*16384 (256 x 64 B).
// One slab = 64 B/row = K=128 = one MFMA k-step.
// T2 granule involution (A): LDS(row R, chunk C) = global granule C ^ ((R>>1)&3);
//   write: linear gload_lds dest + pre-swizzled SOURCE granule;
//   read: chunk = (lane>>4) ^ ((ln15>>1)&3)   [R11/R13: 0 conflicts].
// B frag address (fragment-major): base + n*TS + s*1024 + lane*16 (contiguous).

#define BAR() asm volatile("s_barrier" ::: "memory")
#define WAITV(n) asm volatile("s_waitcnt vmcnt(" #n ")" ::: "memory")
#define LGKM0() asm volatile("s_waitcnt lgkmcnt(0)" ::: "memory")

// fp4 (cbsz:4 / blgp:4): A and B are 4-dword register tuples; acc = 4 x f32
#define MFMA16x16(accv, av, bv) \
  asm("v_mfma_f32_16x16x128_f8f6f4 %0, %1, %2, %0 cbsz:4 blgp:4" \
      : "+v"(accv) : "v"(av), "v"(bv))

__global__ __launch_bounds__(1024, 4) void bgemm_fp4_fm(
    const int8_t* __restrict__ A4, const int8_t* __restrict__ B4,
    const float* __restrict__ scale, const float* __restrict__ bias,
    float* __restrict__ out, int M, int N, int RB /* = IN/2 bytes per row */) {
  __shared__ __align__(16) int8_t lds[65536];

  const int tid = threadIdx.x;
  const int lane = tid & 63;
  const int wid = tid >> 6;      // 0..15
  const int wm = wid >> 2;       // 0..3  (64-row band)
  const int wn = wid & 3;        // 0..3  (64-col band)

  // T1: bijective XCD swizzle (nwg % 8 == 0 here: 32*16 = 512)
  const int nbx = N >> 8;
  const int nwg = (M >> 8) * nbx;
  const int cpx = nwg >> 3;
  const int bid = (int)blockIdx.x;
  const int swz = (bid & 7) * cpx + (bid >> 3);
  const int row0 = (swz / nbx) << 8;
  const int col0 = (swz % nbx) << 8;

  const int ln15 = lane & 15;
  // T2 read-side swizzle (A, verified): chunk byte offset
  const int kcs = (((lane >> 4) ^ ((ln15 >> 1) & 3)) << 4);
  const int aoff = (wm * 64 + ln15) * 64 + kcs;    // + m*1024, m=0..3

  // staging (A only): wave wid stages rows wid*16..wid*16+15 (1 KB)
  const int srow = wid * 16 + (lane >> 2);
  const int sch = (((lane & 3) ^ ((lane >> 3) & 3)) << 4);  // pre-swizzled source granule
  const int ldw = wid << 10;                // wave slot: 1 KB

  const int8_t* aSt = A4 + (size_t)(row0 + srow) * RB + sch;
  // B fragment-major: tile stride TS = RB*16 bytes; wave covers col-tiles
  // (col0>>4)+wn*4+n; lane address is linear (1KB contiguous per load).
  const size_t TS = (size_t)RB * 16;
  const int8_t* bGl = B4 + (size_t)((col0 >> 4) + wn * 4) * TS + lane * 16;

  v4f acc[4][4];
#pragma unroll
  for (int i = 0; i < 4; ++i)
#pragma unroll
    for (int n = 0; n < 4; ++n) { v4f z = {0.f, 0.f, 0.f, 0.f}; acc[i][n] = z; }

  v4i Bv0, Bv1, Bv2, Bv3;   // single set; prefetched cross-barrier (use-then-def)

// 1 global_load_lds per wave per slab (A row-group)
#define STAGE(s) do {                                                                 \
  const int bb_ = ((s) & 3) * 16384;                                                  \
  __builtin_amdgcn_global_load_lds(                                                   \
      (const __attribute__((address_space(1))) uint32_t*)(aSt + (size_t)(s) * 64),    \
      (__attribute__((address_space(3))) uint32_t*)(lds + bb_ + ldw), 16, 0, 0);      \
} while (0)

#define PREF_B(s) do {                                                                \
  const int8_t* p_ = bGl + (size_t)(s) * 1024;                                        \
  Bv0 = *(const v4i*)(p_);          Bv1 = *(const v4i*)(p_ + TS);                     \
  Bv2 = *(const v4i*)(p_ + 2 * TS); Bv3 = *(const v4i*)(p_ + 3 * TS);                 \
} while (0)

// one K=128 slab: A frags from LDS buf q, B from the prefetched registers.
#define COMPUTE(q) do {                                                               \
  const int8_t* ap_ = lds + (q) * 16384 + aoff;                                       \
  __builtin_amdgcn_s_setprio(1);                                                      \
  _Pragma("unroll")                                                                   \
  for (int m_ = 0; m_ < 4; ++m_) {                                                    \
    v4i Av = *(const v4i*)(ap_ + m_ * 1024);                                          \
    MFMA16x16(acc[m_][0], Av, Bv0);                                                   \
    MFMA16x16(acc[m_][1], Av, Bv1);                                                   \
    MFMA16x16(acc[m_][2], Av, Bv2);                                                   \
    MFMA16x16(acc[m_][3], Av, Bv3);                                                   \
  }                                                                                   \
  __builtin_amdgcn_s_setprio(0);                                                      \
} while (0)

  const int NT = RB >> 6;   // 64-byte slabs (K=128 each); 32 for IN=4096

  // ---- prologue: stage A slabs 0,1,2; load B(0); certify A(0); BAR
  STAGE(0); STAGE(1); STAGE(2);
  PREF_B(0);
  WAITV(6);       // queue [A0,A1,A2,B0x4]=7 -> retires A0; B0 rides to COMPUTE(0)
  BAR();

  // ---- main loop: compute slab t, stage A(t+3), prefetch B(t+1) AFTER the
  // MFMAs (use-then-def on Bv: compiler orders; load crosses the barrier and
  // lands before its first use next body). WAITV(6) certifies A(t+1).
  for (int t = 0; t < NT - 3; ++t) {
    STAGE(t + 3);
    COMPUTE(t & 3);
    PREF_B(t + 1);
    LGKM0();
    WAITV(6);
    BAR();
  }
  // tail: no A staging
  COMPUTE((NT - 3) & 3); PREF_B(NT - 2); LGKM0(); WAITV(4); BAR();
  COMPUTE((NT - 2) & 3); PREF_B(NT - 1); LGKM0(); WAITV(4); BAR();
  COMPUTE((NT - 1) & 3);
  asm volatile("s_nop 7\n\ts_nop 7" :::);   // MFMA write -> VALU read hazard guard

  // ---- epilogue: 16x16 C/D layout: col = lane&15, row = (lane>>4)*4 + reg
  // (verified). acc[i] <-> rows wm*64 + i*16.
  const int cw = col0 + wn * 64;
  float scv[4], biv[4];
#pragma unroll
  for (int n = 0; n < 4; ++n) {
    int c = cw + n * 16 + ln15;
    scv[n] = scale[c];
    biv[n] = bias[c];
  }
#pragma unroll
  for (int i = 0; i < 4; ++i) {
    const int r0 = row0 + wm * 64 + i * 16 + ((lane >> 4) << 2);
#pragma unroll
    for (int reg = 0; reg < 4; ++reg) {
      float* orow = out + (size_t)(r0 + reg) * N;
#pragma unroll
      for (int n = 0; n < 4; ++n)
        orow[cw + n * 16 + ln15] = fmaf(acc[i][n][reg], scv[n], biv[n]);
    }
  }

#undef STAGE
#undef PREF_B
#undef COMPUTE
}

// ======================= launch =======================
extern "C" void kernel_launch(void* const* d_in, const int* in_sizes, int n_in,
                              void* d_out, int out_size, void* d_ws, size_t ws_size,
                              hipStream_t stream) {
  const float* x = (const float*)d_in[0];
  const float* w = (const float*)d_in[1];
  const float* gamma = (const float*)d_in[2];
  const float* beta = (const float*)d_in[3];
  const float* mean = (const float*)d_in[4];
  const float* var = (const float*)d_in[5];
  float* out = (float*)d_out;

  const int OUT = in_sizes[2];            // 4096
  const int IN = in_sizes[1] / OUT;       // 4096
  const int B = in_sizes[0] / IN;         // 8192
  const int RB = IN / 2;                  // packed fp4 bytes per row
  const int GR = IN / 32;                 // 16B granules per row

  int8_t* a4 = (int8_t*)d_ws;
  int8_t* b4 = a4 + (size_t)B * RB;
  float* scale = (float*)(b4 + (size_t)OUT * RB);
  float* bias = scale + OUT;

  const int n32x = B * GR;
  const int n32w = OUT * GR;
  pack_sign_fp4_kernel<<<(n32x + 255) / 256, 256, 0, stream>>>(
      (const uint4*)x, (uint4*)a4, n32x);
  pack_sign_fp4_wtile<<<(n32w + 255) / 256, 256, 0, stream>>>(
      (const uint4*)w, (uint4*)b4, n32w, GR);
  bn_prep_kernel<<<(OUT + 255) / 256, 256, 0, stream>>>(
      gamma, beta, mean, var, scale, bias, OUT);

  dim3 grid((B >> 8) * (OUT >> 8));
  bgemm_fp4_fm<<<grid, 1024, 0, stream>>>(a4, b4, scale, bias, out, B, OUT, RB);
}

// Round 16
// 132.272 us; speedup vs baseline: 1.7087x; 1.0296x over previous
//
#include <hip/hip_runtime.h>
#include <stdint.h>
#include <stddef.h>

// BinarizeLinearWithFoldedBN on MI355X (gfx950).
// out[b,o] = dot(sign(x[b,:]), sign(w[o,:])) * scale[o] + bias[o]
//   scale = gamma/sqrt(var+eps), bias = beta - mean*scale (exact BN algebra)
// GEMM: R13 kernel VERBATIM (best measured: 75 us, MfmaUtil 36.5%, 0 conflicts).
//   FP4 (+/-1 e2m1) via v_mfma_f32_16x16x128_f8f6f4 cbsz:4 blgp:4, 256x256
//   tile, 16 waves, 4-buf 64B-slab rotation, distance-3 prefetch, counted
//   vmcnt, T1 XCD swizzle + T2 granule involution + T5 setprio.
// Pack: NEW fused coalesced kernel -- one uint4 (4 floats) per thread-step,
//   lane-consecutive reads (1KB/wave/instr), u16 nibble-packed stores.

#define BN_EPS 1e-5f
typedef int   v4i __attribute__((ext_vector_type(4)));
typedef float v4f __attribute__((ext_vector_type(4)));
typedef unsigned int u32;

// ---------------- BN fold ----------------
__global__ void bn_prep_kernel(const float* __restrict__ g, const float* __restrict__ b,
                               const float* __restrict__ m, const float* __restrict__ v,
                               float* __restrict__ scale, float* __restrict__ bias, int n) {
  int i = blockIdx.x * blockDim.x + threadIdx.x;
  if (i >= n) return;
  float s = g[i] * rsqrtf(v[i] + BN_EPS);
  scale[i] = s;
  bias[i] = b[i] - m[i] * s;
}

// ---------------- fused coalesced pack: f32 signs -> fp4 e2m1 +/-1 nibbles ----
// One uint4 = 4 floats -> one u16 (element i at nibble i; +1 -> 0x2, -1 -> 0xA).
// Byte layout identical to previous pack (byte k holds elements 2k, 2k+1).
// Grid-stride over x then w; reads 16B/lane lane-consecutive, writes 2B/lane.
__global__ __launch_bounds__(256) void pack_sign_fp4_fused(
    const uint4* __restrict__ x, unsigned short* __restrict__ a4, int nx4,
    const uint4* __restrict__ w, unsigned short* __restrict__ b4, int nw4) {
  const int stride = gridDim.x * blockDim.x;
  const int ntot = nx4 + nw4;
  for (int i = blockIdx.x * blockDim.x + threadIdx.x; i < ntot; i += stride) {
    const bool isx = (i < nx4);
    const int j = isx ? i : i - nx4;
    uint4 u = isx ? x[j] : w[j];
    unsigned short v = (unsigned short)(0x2222u
        | ((u.x >> 28) & 0x8u)      // sign(e0) << 3
        | ((u.y >> 24) & 0x80u)     // sign(e1) << 7
        | ((u.z >> 20) & 0x800u)    // sign(e2) << 11
        | ((u.w >> 16) & 0x8000u)); // sign(e3) << 15
    if (isx) a4[j] = v; else b4[j] = v;
  }
}

// ---------------- fp4 MFMA GEMM (R13 verbatim) ----------------
// Row bytes RB = IN/2. LDS (128 KiB): A slab buf q (q=0..3): q*16384 (256 x 64 B);
// B slab buf q: 65536 + q*16384. One slab = 64 B/row = K=128 = one MFMA k-step.
// T2 granule involution: LDS(row R, chunk C) = global granule C ^ ((R>>1)&3);
//   write: linear gload_lds dest + pre-swizzled SOURCE granule;
//   read: chunk = (lane>>4) ^ ((ln15>>1)&3)   [0 conflicts, measured].

#define BAR() asm volatile("s_barrier" ::: "memory")
#define WAITV(n) asm volatile("s_waitcnt vmcnt(" #n ")" ::: "memory")
#define LGKM0() asm volatile("s_waitcnt lgkmcnt(0)" ::: "memory")

// fp4 (cbsz:4 / blgp:4): A and B are 4-dword register tuples; acc = 4 x f32
#define MFMA16x16(accv, av, bv) \
  asm("v_mfma_f32_16x16x128_f8f6f4 %0, %1, %2, %0 cbsz:4 blgp:4" \
      : "+v"(accv) : "v"(av), "v"(bv))

__global__ __launch_bounds__(1024, 4) void bgemm_fp4_w16(
    const int8_t* __restrict__ A4, const int8_t* __restrict__ B4,
    const float* __restrict__ scale, const float* __restrict__ bias,
    float* __restrict__ out, int M, int N, int RB /* = IN/2 bytes per row */) {
  __shared__ __align__(16) int8_t lds[131072];

  const int tid = threadIdx.x;
  const int lane = tid & 63;
  const int wid = tid >> 6;      // 0..15
  const int wm = wid >> 2;       // 0..3  (64-row band)
  const int wn = wid & 3;        // 0..3  (64-col band)

  // T1: bijective XCD swizzle (nwg % 8 == 0 here: 32*16 = 512)
  const int nbx = N >> 8;
  const int nwg = (M >> 8) * nbx;
  const int cpx = nwg >> 3;
  const int bid = (int)blockIdx.x;
  const int swz = (bid & 7) * cpx + (bid >> 3);
  const int row0 = (swz / nbx) << 8;
  const int col0 = (swz % nbx) << 8;

  const int ln15 = lane & 15;
  // T2 read-side swizzle (verified): chunk byte offset
  const int kcs = (((lane >> 4) ^ ((ln15 >> 1) & 3)) << 4);
  const int aoff = (wm * 64 + ln15) * 64 + kcs;    // + m*1024, m=0..3
  const int boff = (wn * 64 + ln15) * 64 + kcs;    // + n*1024, n=0..3

  // staging: wave wid stages rows wid*16..wid*16+15 of A and of B (1 KB each)
  const int srow = wid * 16 + (lane >> 2);
  const int sch = (((lane & 3) ^ ((lane >> 3) & 3)) << 4);  // pre-swizzled source granule
  const int ldw = wid << 10;                // wave slot: 1 KB

  const int8_t* aSt = A4 + (size_t)(row0 + srow) * RB + sch;
  const int8_t* bSt = B4 + (size_t)(col0 + srow) * RB + sch;

  v4f acc[4][4];
#pragma unroll
  for (int i = 0; i < 4; ++i)
#pragma unroll
    for (int n = 0; n < 4; ++n) { v4f z = {0.f, 0.f, 0.f, 0.f}; acc[i][n] = z; }

// 2 global_load_lds per wave per slab (A row-group + B row-group)
#define STAGE(s) do {                                                                 \
  const int bb_ = ((s) & 3) * 16384;                                                  \
  __builtin_amdgcn_global_load_lds(                                                   \
      (const __attribute__((address_space(1))) uint32_t*)(aSt + (size_t)(s) * 64),    \
      (__attribute__((address_space(3))) uint32_t*)(lds + bb_ + ldw), 16, 0, 0);      \
  __builtin_amdgcn_global_load_lds(                                                   \
      (const __attribute__((address_space(1))) uint32_t*)(bSt + (size_t)(s) * 64),    \
      (__attribute__((address_space(3))) uint32_t*)(lds + 65536 + bb_ + ldw), 16, 0, 0); \
} while (0)

// one K=128 slab from buf q: 4 B reads (reused by 4 m-tiles) + per-m A read
// + 4 MFMAs. Register deps give the compiler counted lgkmcnt under the MFMAs.
#define COMPUTE(q) do {                                                               \
  const int8_t* ap_ = lds + (q) * 16384 + aoff;                                       \
  const int8_t* bp_ = lds + 65536 + (q) * 16384 + boff;                               \
  v4i Bv0 = *(const v4i*)(bp_);        v4i Bv1 = *(const v4i*)(bp_ + 1024);           \
  v4i Bv2 = *(const v4i*)(bp_ + 2048); v4i Bv3 = *(const v4i*)(bp_ + 3072);           \
  __builtin_amdgcn_s_setprio(1);                                                      \
  _Pragma("unroll")                                                                   \
  for (int m_ = 0; m_ < 4; ++m_) {                                                    \
    v4i Av = *(const v4i*)(ap_ + m_ * 1024);                                          \
    MFMA16x16(acc[m_][0], Av, Bv0);                                                   \
    MFMA16x16(acc[m_][1], Av, Bv1);                                                   \
    MFMA16x16(acc[m_][2], Av, Bv2);                                                   \
    MFMA16x16(acc[m_][3], Av, Bv3);                                                   \
  }                                                                                   \
  __builtin_amdgcn_s_setprio(0);                                                      \
} while (0)

  const int NT = RB >> 6;   // 64-byte slabs (K=128 each); 32 for IN=4096

  // ---- prologue: prefetch slabs 0,1,2 (6 loads); certify slab 0 (4 left); BAR
  STAGE(0); STAGE(1); STAGE(2);
  WAITV(4);
  BAR();

  // ---- main loop: compute slab t, stage slab t+3 into buf (t+3)&3 = (t-1)&3,
  // whose readers drained at body t-1's LGKM0+BAR.
  for (int t = 0; t < NT - 3; ++t) {
    STAGE(t + 3);     // outstanding: slabs t+1,t+2,t+3 = 6 loads
    COMPUTE(t & 3);
    LGKM0();          // my LDS reads of buf t&3 done -> reusable after BAR
    WAITV(4);         // slab t+1's 2 loads retired (6 -> 4)
    BAR();            // certifies both for every wave
  }
  // tail: drain 4 -> 2 -> 0
  COMPUTE((NT - 3) & 3); LGKM0(); WAITV(2); BAR();
  COMPUTE((NT - 2) & 3); LGKM0(); WAITV(0); BAR();
  COMPUTE((NT - 1) & 3);
  asm volatile("s_nop 7\n\ts_nop 7" :::);   // MFMA write -> VALU read hazard guard

  // ---- epilogue: 16x16 C/D layout: col = lane&15, row = (lane>>4)*4 + reg
  // (verified). acc[i] <-> rows wm*64 + i*16.
  const int cw = col0 + wn * 64;
  float scv[4], biv[4];
#pragma unroll
  for (int n = 0; n < 4; ++n) {
    int c = cw + n * 16 + ln15;
    scv[n] = scale[c];
    biv[n] = bias[c];
  }
#pragma unroll
  for (int i = 0; i < 4; ++i) {
    const int r0 = row0 + wm * 64 + i * 16 + ((lane >> 4) << 2);
#pragma unroll
    for (int reg = 0; reg < 4; ++reg) {
      float* orow = out + (size_t)(r0 + reg) * N;
#pragma unroll
      for (int n = 0; n < 4; ++n)
        orow[cw + n * 16 + ln15] = fmaf(acc[i][n][reg], scv[n], biv[n]);
    }
  }

#undef STAGE
#undef COMPUTE
}

// ======================= launch =======================
extern "C" void kernel_launch(void* const* d_in, const int* in_sizes, int n_in,
                              void* d_out, int out_size, void* d_ws, size_t ws_size,
                              hipStream_t stream) {
  const float* x = (const float*)d_in[0];
  const float* w = (const float*)d_in[1];
  const float* gamma = (const float*)d_in[2];
  const float* beta = (const float*)d_in[3];
  const float* mean = (const float*)d_in[4];
  const float* var = (const float*)d_in[5];
  float* out = (float*)d_out;

  const int OUT = in_sizes[2];            // 4096
  const int IN = in_sizes[1] / OUT;       // 4096
  const int B = in_sizes[0] / IN;         // 8192
  const int RB = IN / 2;                  // packed fp4 bytes per row

  int8_t* a4 = (int8_t*)d_ws;
  int8_t* b4 = a4 + (size_t)B * RB;
  float* scale = (float*)(b4 + (size_t)OUT * RB);
  float* bias = scale + OUT;

  const int nx4 = B * (IN / 4);           // uint4 count for x
  const int nw4 = OUT * (IN / 4);         // uint4 count for w
  pack_sign_fp4_fused<<<2048, 256, 0, stream>>>(
      (const uint4*)x, (unsigned short*)a4, nx4,
      (const uint4*)w, (unsigned short*)b4, nw4);
  bn_prep_kernel<<<(OUT + 255) / 256, 256, 0, stream>>>(
      gamma, beta, mean, var, scale, bias, OUT);

  dim3 grid((B >> 8) * (OUT >> 8));
  bgemm_fp4_w16<<<grid, 1024, 0, stream>>>(a4, b4, scale, bias, out, B, OUT, RB);
}

// Round 17
// 123.380 us; speedup vs baseline: 1.8318x; 1.0721x over previous
//
#include <hip/hip_runtime.h>
#include <stdint.h>
#include <stddef.h>

// BinarizeLinearWithFoldedBN on MI355X (gfx950).
// out[b,o] = dot(sign(x[b,:]), sign(w[o,:])) * scale[o] + bias[o]
//   scale = gamma/sqrt(var+eps), bias = beta - mean*scale (exact BN algebra)
// GEMM: R13 kernel VERBATIM (best measured: 75 us, MfmaUtil 36.5%, 0 conflicts).
//   FP4 (+/-1 e2m1) via v_mfma_f32_16x16x128_f8f6f4 cbsz:4 blgp:4, 256x256
//   tile, 16 waves, 4-buf 64B-slab rotation, distance-3 prefetch, counted
//   vmcnt, T1 XCD swizzle + T2 granule involution + T5 setprio.
// Pack: chunked kernel with coalesced loads (1KB/wave-instr) AND MLP=8
//   (8 independent unrolled loads/thread), block-uniform x/w select.
//   Nibble math verified in R16 (absmax 2.0); layout bit-identical.

#define BN_EPS 1e-5f
typedef int   v4i __attribute__((ext_vector_type(4)));
typedef float v4f __attribute__((ext_vector_type(4)));
typedef unsigned int u32;

// ---------------- BN fold ----------------
__global__ void bn_prep_kernel(const float* __restrict__ g, const float* __restrict__ b,
                               const float* __restrict__ m, const float* __restrict__ v,
                               float* __restrict__ scale, float* __restrict__ bias, int n) {
  int i = blockIdx.x * blockDim.x + threadIdx.x;
  if (i >= n) return;
  float s = g[i] * rsqrtf(v[i] + BN_EPS);
  scale[i] = s;
  bias[i] = b[i] - m[i] * s;
}

// ---------------- chunked coalesced pack: f32 signs -> fp4 e2m1 +/-1 nibbles ----
// Block b owns 2048 contiguous uint4s (32 KB in / 4 KB out). Thread: 8
// independent loads at base + j*256 + tid (lane-consecutive -> 1KB/wave/instr,
// MLP=8), 8 u16 stores at the same linear index (128 B/wave contiguous).
// u16 i holds elements 4i..4i+3 (nibble k = element k; +1 -> 0x2, -1 -> 0xA).
__global__ __launch_bounds__(256) void pack_sign_fp4_chunked(
    const uint4* __restrict__ x, unsigned short* __restrict__ a16, int nblkx,
    const uint4* __restrict__ w, unsigned short* __restrict__ b16) {
  const int tid = threadIdx.x;
  const int b = blockIdx.x;
  const bool isx = (b < nblkx);                 // block-uniform, no divergence
  const uint4* src = isx ? x : w;
  unsigned short* dst = isx ? a16 : b16;
  const int base = (isx ? b : b - nblkx) * 2048;

  uint4 u[8];
#pragma unroll
  for (int j = 0; j < 8; ++j) u[j] = src[base + j * 256 + tid];
#pragma unroll
  for (int j = 0; j < 8; ++j) {
    unsigned short v = (unsigned short)(0x2222u
        | ((u[j].x >> 28) & 0x8u)
        | ((u[j].y >> 24) & 0x80u)
        | ((u[j].z >> 20) & 0x800u)
        | ((u[j].w >> 16) & 0x8000u));
    dst[base + j * 256 + tid] = v;
  }
}

// ---------------- fp4 MFMA GEMM (R13 verbatim) ----------------
// Row bytes RB = IN/2. LDS (128 KiB): A slab buf q (q=0..3): q*16384 (256 x 64 B);
// B slab buf q: 65536 + q*16384. One slab = 64 B/row = K=128 = one MFMA k-step.
// T2 granule involution: LDS(row R, chunk C) = global granule C ^ ((R>>1)&3);
//   write: linear gload_lds dest + pre-swizzled SOURCE granule;
//   read: chunk = (lane>>4) ^ ((ln15>>1)&3)   [0 conflicts, measured].

#define BAR() asm volatile("s_barrier" ::: "memory")
#define WAITV(n) asm volatile("s_waitcnt vmcnt(" #n ")" ::: "memory")
#define LGKM0() asm volatile("s_waitcnt lgkmcnt(0)" ::: "memory")

// fp4 (cbsz:4 / blgp:4): A and B are 4-dword register tuples; acc = 4 x f32
#define MFMA16x16(accv, av, bv) \
  asm("v_mfma_f32_16x16x128_f8f6f4 %0, %1, %2, %0 cbsz:4 blgp:4" \
      : "+v"(accv) : "v"(av), "v"(bv))

__global__ __launch_bounds__(1024, 4) void bgemm_fp4_w16(
    const int8_t* __restrict__ A4, const int8_t* __restrict__ B4,
    const float* __restrict__ scale, const float* __restrict__ bias,
    float* __restrict__ out, int M, int N, int RB /* = IN/2 bytes per row */) {
  __shared__ __align__(16) int8_t lds[131072];

  const int tid = threadIdx.x;
  const int lane = tid & 63;
  const int wid = tid >> 6;      // 0..15
  const int wm = wid >> 2;       // 0..3  (64-row band)
  const int wn = wid & 3;        // 0..3  (64-col band)

  // T1: bijective XCD swizzle (nwg % 8 == 0 here: 32*16 = 512)
  const int nbx = N >> 8;
  const int nwg = (M >> 8) * nbx;
  const int cpx = nwg >> 3;
  const int bid = (int)blockIdx.x;
  const int swz = (bid & 7) * cpx + (bid >> 3);
  const int row0 = (swz / nbx) << 8;
  const int col0 = (swz % nbx) << 8;

  const int ln15 = lane & 15;
  // T2 read-side swizzle (verified): chunk byte offset
  const int kcs = (((lane >> 4) ^ ((ln15 >> 1) & 3)) << 4);
  const int aoff = (wm * 64 + ln15) * 64 + kcs;    // + m*1024, m=0..3
  const int boff = (wn * 64 + ln15) * 64 + kcs;    // + n*1024, n=0..3

  // staging: wave wid stages rows wid*16..wid*16+15 of A and of B (1 KB each)
  const int srow = wid * 16 + (lane >> 2);
  const int sch = (((lane & 3) ^ ((lane >> 3) & 3)) << 4);  // pre-swizzled source granule
  const int ldw = wid << 10;                // wave slot: 1 KB

  const int8_t* aSt = A4 + (size_t)(row0 + srow) * RB + sch;
  const int8_t* bSt = B4 + (size_t)(col0 + srow) * RB + sch;

  v4f acc[4][4];
#pragma unroll
  for (int i = 0; i < 4; ++i)
#pragma unroll
    for (int n = 0; n < 4; ++n) { v4f z = {0.f, 0.f, 0.f, 0.f}; acc[i][n] = z; }

// 2 global_load_lds per wave per slab (A row-group + B row-group)
#define STAGE(s) do {                                                                 \
  const int bb_ = ((s) & 3) * 16384;                                                  \
  __builtin_amdgcn_global_load_lds(                                                   \
      (const __attribute__((address_space(1))) uint32_t*)(aSt + (size_t)(s) * 64),    \
      (__attribute__((address_space(3))) uint32_t*)(lds + bb_ + ldw), 16, 0, 0);      \
  __builtin_amdgcn_global_load_lds(                                                   \
      (const __attribute__((address_space(1))) uint32_t*)(bSt + (size_t)(s) * 64),    \
      (__attribute__((address_space(3))) uint32_t*)(lds + 65536 + bb_ + ldw), 16, 0, 0); \
} while (0)

// one K=128 slab from buf q: 4 B reads (reused by 4 m-tiles) + per-m A read
// + 4 MFMAs. Register deps give the compiler counted lgkmcnt under the MFMAs.
#define COMPUTE(q) do {                                                               \
  const int8_t* ap_ = lds + (q) * 16384 + aoff;                                       \
  const int8_t* bp_ = lds + 65536 + (q) * 16384 + boff;                               \
  v4i Bv0 = *(const v4i*)(bp_);        v4i Bv1 = *(const v4i*)(bp_ + 1024);           \
  v4i Bv2 = *(const v4i*)(bp_ + 2048); v4i Bv3 = *(const v4i*)(bp_ + 3072);           \
  __builtin_amdgcn_s_setprio(1);                                                      \
  _Pragma("unroll")                                                                   \
  for (int m_ = 0; m_ < 4; ++m_) {                                                    \
    v4i Av = *(const v4i*)(ap_ + m_ * 1024);                                          \
    MFMA16x16(acc[m_][0], Av, Bv0);                                                   \
    MFMA16x16(acc[m_][1], Av, Bv1);                                                   \
    MFMA16x16(acc[m_][2], Av, Bv2);                                                   \
    MFMA16x16(acc[m_][3], Av, Bv3);                                                   \
  }                                                                                   \
  __builtin_amdgcn_s_setprio(0);                                                      \
} while (0)

  const int NT = RB >> 6;   // 64-byte slabs (K=128 each); 32 for IN=4096

  // ---- prologue: prefetch slabs 0,1,2 (6 loads); certify slab 0 (4 left); BAR
  STAGE(0); STAGE(1); STAGE(2);
  WAITV(4);
  BAR();

  // ---- main loop: compute slab t, stage slab t+3 into buf (t+3)&3 = (t-1)&3,
  // whose readers drained at body t-1's LGKM0+BAR.
  for (int t = 0; t < NT - 3; ++t) {
    STAGE(t + 3);     // outstanding: slabs t+1,t+2,t+3 = 6 loads
    COMPUTE(t & 3);
    LGKM0();          // my LDS reads of buf t&3 done -> reusable after BAR
    WAITV(4);         // slab t+1's 2 loads retired (6 -> 4)
    BAR();            // certifies both for every wave
  }
  // tail: drain 4 -> 2 -> 0
  COMPUTE((NT - 3) & 3); LGKM0(); WAITV(2); BAR();
  COMPUTE((NT - 2) & 3); LGKM0(); WAITV(0); BAR();
  COMPUTE((NT - 1) & 3);
  asm volatile("s_nop 7\n\ts_nop 7" :::);   // MFMA write -> VALU read hazard guard

  // ---- epilogue: 16x16 C/D layout: col = lane&15, row = (lane>>4)*4 + reg
  // (verified). acc[i] <-> rows wm*64 + i*16.
  const int cw = col0 + wn * 64;
  float scv[4], biv[4];
#pragma unroll
  for (int n = 0; n < 4; ++n) {
    int c = cw + n * 16 + ln15;
    scv[n] = scale[c];
    biv[n] = bias[c];
  }
#pragma unroll
  for (int i = 0; i < 4; ++i) {
    const int r0 = row0 + wm * 64 + i * 16 + ((lane >> 4) << 2);
#pragma unroll
    for (int reg = 0; reg < 4; ++reg) {
      float* orow = out + (size_t)(r0 + reg) * N;
#pragma unroll
      for (int n = 0; n < 4; ++n)
        orow[cw + n * 16 + ln15] = fmaf(acc[i][n][reg], scv[n], biv[n]);
    }
  }

#undef STAGE
#undef COMPUTE
}

// ======================= launch =======================
extern "C" void kernel_launch(void* const* d_in, const int* in_sizes, int n_in,
                              void* d_out, int out_size, void* d_ws, size_t ws_size,
                              hipStream_t stream) {
  const float* x = (const float*)d_in[0];
  const float* w = (const float*)d_in[1];
  const float* gamma = (const float*)d_in[2];
  const float* beta = (const float*)d_in[3];
  const float* mean = (const float*)d_in[4];
  const float* var = (const float*)d_in[5];
  float* out = (float*)d_out;

  const int OUT = in_sizes[2];            // 4096
  const int IN = in_sizes[1] / OUT;       // 4096
  const int B = in_sizes[0] / IN;         // 8192
  const int RB = IN / 2;                  // packed fp4 bytes per row

  int8_t* a4 = (int8_t*)d_ws;
  int8_t* b4 = a4 + (size_t)B * RB;
  float* scale = (float*)(b4 + (size_t)OUT * RB);
  float* bias = scale + OUT;

  const int nx4 = B * (IN / 4);           // uint4 count for x (8.39M)
  const int nw4 = OUT * (IN / 4);         // uint4 count for w (4.19M)
  const int nblkx = nx4 / 2048;           // 4096 (exact)
  const int nblkw = nw4 / 2048;           // 2048 (exact)
  pack_sign_fp4_chunked<<<nblkx + nblkw, 256, 0, stream>>>(
      (const uint4*)x, (unsigned short*)a4, nblkx,
      (const uint4*)w, (unsigned short*)b4);
  bn_prep_kernel<<<(OUT + 255) / 256, 256, 0, stream>>>(
      gamma, beta, mean, var, scale, bias, OUT);

  dim3 grid((B >> 8) * (OUT >> 8));
  bgemm_fp4_w16<<<grid, 1024, 0, stream>>>(a4, b4, scale, bias, out, B, OUT, RB);
}